// Round 2
// baseline (888.389 us; speedup 1.0000x reference)
//
#include <hip/hip_runtime.h>

#define NSET 38
#define NSNAP 9
#define PART (NSNAP*NSET*64)   // 21888 floats of partial per block

typedef unsigned long long ull;

// kA<PPB>: PPB points per block, 256 threads.
// LDS: zt[PPB][68] f32 | addend[PPB][48] f32 | memb[PPB] u64  = PPB*472 bytes
template<int PPB>
__global__ __launch_bounds__(256) void kA(
    const int* __restrict__ x, const float* __restrict__ w0,
    const float* __restrict__ cw, const float* __restrict__ cb,
    const float* __restrict__ pa, float* __restrict__ partial)
{
  extern __shared__ __align__(16) char smem[];
  float* zt = (float*)smem;                 // [PPB][68] (+4 pad per row)
  float* addend = zt + PPB*68;              // [PPB][48]
  ull*   memb = (ull*)(addend + PPB*48);    // [PPB]

  const int tid = threadIdx.x;
  const int pl  = tid & (PPB-1);
  const int p   = blockIdx.x * PPB + pl;

  if (tid < PPB) {
    ull m = 0;
    #pragma unroll
    for (int s = 0; s < NSET; ++s)
      m |= (ull)(x[s*65536 + p] == 1) << s;
    memb[tid] = m;
  }
  __syncthreads();

  // mask addend table, built once, reused for all 9 snapshots
  #pragma unroll 1
  for (int i = tid; i < PPB*48; i += 256) {
    int pp = i / 48;
    int j  = i - pp*48;
    addend[i] = (j < NSET && ((memb[pp] >> j) & 1ull)) ? 0.f : -1e38f;
  }

  // conv0 (weights via scalar loads; px,py per-thread)
  float z[64], zn[64];
  {
    float px = -1.f + (2.f/255.f)*(float)(p & 255);
    float py = -1.f + (2.f/255.f)*(float)(p >> 8);
    #pragma unroll
    for (int d = 0; d < 64; ++d)
      zn[d] = fmaf(px, w0[2*d], fmaf(py, w0[2*d+1], cb[d]));
  }

  const int d0 = tid & 63;
  const int g  = tid >> 6;            // wave id: 12 sets each (48 padded)
  float* myrow = &zt[pl*68];

  #pragma unroll 1
  for (int s = 0; s < NSNAP; ++s) {
    // PReLU (pool in PReLU domain; monotone, conv-domain max recovered in kB)
    #pragma unroll
    for (int d = 0; d < 64; ++d) {
      float zv = zn[d];
      z[d] = zv > 0.f ? zv : pa[(s<<6)+d]*zv;
    }
    __syncthreads();   // prior pool reads done
    if (tid < PPB) {
      #pragma unroll
      for (int q = 0; q < 16; ++q)
        *(float4*)&myrow[q<<2] = make_float4(z[4*q], z[4*q+1], z[4*q+2], z[4*q+3]);
    }
    __syncthreads();   // zt (and, first iter, addend) ready

    // masked-max partials: thread (d0,g) pools 12 sets over PPB points
    float run[12];
    #pragma unroll
    for (int j = 0; j < 12; ++j) run[j] = -3e38f;
    #pragma unroll 1
    for (int pp = 0; pp < PPB; pp += 2) {
      float v0 = zt[pp*68 + d0];
      float v1 = zt[(pp+1)*68 + d0];
      const float4* a0 = (const float4*)&addend[pp*48 + g*12];
      const float4* a1 = (const float4*)&addend[(pp+1)*48 + g*12];
      #pragma unroll
      for (int q = 0; q < 3; ++q) {
        float4 x0 = a0[q], x1 = a1[q];
        run[4*q+0] = fmaxf(fmaxf(run[4*q+0], v0 + x0.x), v1 + x1.x);
        run[4*q+1] = fmaxf(fmaxf(run[4*q+1], v0 + x0.y), v1 + x1.y);
        run[4*q+2] = fmaxf(fmaxf(run[4*q+2], v0 + x0.z), v1 + x1.z);
        run[4*q+3] = fmaxf(fmaxf(run[4*q+3], v0 + x0.w), v1 + x1.w);
      }
    }
    {
      float* pb = partial + (size_t)blockIdx.x*PART + s*(NSET*64) + d0;
      #pragma unroll
      for (int j = 0; j < 12; ++j) {
        int set = g*12 + j;
        if (set < NSET) pb[set*64] = run[j];
      }
    }

    if (s < 8) {
      // next conv layer: weights wave-uniform -> s_load (no LDS)
      const float* W = cw + (s << 12);
      #pragma unroll 8
      for (int d = 0; d < 64; ++d) {
        float acc = cb[((s+1)<<6) + d];
        #pragma unroll
        for (int k = 0; k < 64; ++k)
          acc = fmaf(z[k], W[(d<<6) + k], acc);
        zn[d] = acc;
      }
    }
  }
}

// zero-point snapshots: conv-domain and prelu-domain, 9 x 64 each
__global__ void kZ(const float* __restrict__ cw, const float* __restrict__ cb,
                   const float* __restrict__ pa,
                   float* __restrict__ zsc, float* __restrict__ zsp)
{
  __shared__ float zl[64];
  int d = threadIdx.x;  // 64 threads
  float z = cb[d];
  #pragma unroll 1
  for (int s = 0; s < NSNAP; ++s) {
    zsc[(s<<6) + d] = z;
    float a = pa[(s<<6) + d];
    float zp = z > 0.f ? z : a*z;
    zsp[(s<<6) + d] = zp;
    if (s < 8) {
      __syncthreads();
      zl[d] = zp;
      __syncthreads();
      float acc = cb[((s+1)<<6) + d];
      for (int k = 0; k < 64; ++k)
        acc = fmaf(zl[k], cw[(s<<12) + (d<<6) + k], acc);
      z = acc;
    }
  }
}

// reduce block partials -> pooled -> feat (conv & prelu snapshots)
__global__ void kB(const float* __restrict__ partial, int nblk,
                   const float* __restrict__ zsc, const float* __restrict__ zsp,
                   const float* __restrict__ pa, float* __restrict__ feat)
{
  int idx = blockIdx.x*256 + threadIdx.x;
  if (idx >= NSNAP*NSET*64) return;
  int s = idx / (NSET*64);
  int r = idx - s*(NSET*64);
  int set = r >> 6;
  int d = r & 63;
  float mx = -3e38f;
  const float* p0 = partial + idx;   // layout [blk][s][set][d] matches idx
  #pragma unroll 4
  for (int blk = 0; blk < nblk; ++blk)
    mx = fmaxf(mx, p0[(size_t)blk*PART]);
  int b = set / 19, c = set - b*19;
  float even_v, odd_v;
  if (mx < -5e37f) {                 // empty set -> zero-point snapshot
    even_v = zsc[(s<<6) + d];
    odd_v  = zsp[(s<<6) + d];
  } else {
    odd_v = mx;                      // prelu-domain max
    float a = pa[(s<<6) + d];
    even_v = mx > 0.f ? mx : mx / a; // inverse prelu
  }
  size_t fb = ((size_t)b*18 + 2*s)*1216 + c*64 + d;
  feat[fb] = even_v;
  feat[fb + 1216] = odd_v;
}

// out[b][17-lr][srow] = scale*<feat[b][lr], fcw[lr][srow]> + fcb[lr][srow]
__global__ __launch_bounds__(256) void kC(const float* __restrict__ feat,
    const float* __restrict__ fcw, const float* __restrict__ fcb,
    float* __restrict__ out)
{
  __shared__ float f0[1216], f1[1216];
  int lr = blockIdx.y;
  int chunk = blockIdx.x;       // 0..31, 16 rows each
  int tid = threadIdx.x;
  for (int i = tid; i < 1216; i += 256) {
    f0[i] = feat[(size_t)(0*18 + lr)*1216 + i];
    f1[i] = feat[(size_t)(1*18 + lr)*1216 + i];
  }
  __syncthreads();
  int wv = tid >> 6, lane = tid & 63;
  float scale = 1.f / sqrtf(1216.f);
  int l = 17 - lr;
  #pragma unroll 1
  for (int rr = 0; rr < 4; ++rr) {
    int srow = (chunk << 4) + (wv << 2) + rr;
    const float* wrow = fcw + ((size_t)lr*512 + srow)*1216;
    float pp0 = 0.f, pp1 = 0.f;
    #pragma unroll
    for (int k = 0; k < 19; ++k) {
      float w = wrow[(k<<6) + lane];
      pp0 = fmaf(w, f0[(k<<6) + lane], pp0);
      pp1 = fmaf(w, f1[(k<<6) + lane], pp1);
    }
    #pragma unroll
    for (int off = 32; off; off >>= 1) {
      pp0 += __shfl_xor(pp0, off, 64);
      pp1 += __shfl_xor(pp1, off, 64);
    }
    if (lane == 0) {
      float b = fcb[lr*512 + srow];
      out[((size_t)0*18 + l)*512 + srow] = fmaf(scale, pp0, b);
      out[((size_t)1*18 + l)*512 + srow] = fmaf(scale, pp1, b);
    }
  }
}

extern "C" void kernel_launch(void* const* d_in, const int* in_sizes, int n_in,
                              void* d_out, int out_size, void* d_ws, size_t ws_size,
                              hipStream_t stream) {
  const int*   x   = (const int*)d_in[0];
  const float* w0  = (const float*)d_in[1];
  const float* cw  = (const float*)d_in[2];
  const float* cb  = (const float*)d_in[3];
  const float* pa  = (const float*)d_in[4];
  const float* fcw = (const float*)d_in[5];
  const float* fcb = (const float*)d_in[6];
  float* ws = (float*)d_ws;
  float* out = (float*)d_out;

  const size_t tail = (size_t)NSNAP*64*2 + (size_t)2*18*1216;  // zsc+zsp+feat
  const size_t need512 = ((size_t)512*PART + tail)*4;

  int nblk;
  if (ws_size >= need512) nblk = 512; else nblk = 256;

  float* partial = ws;
  float* zsc  = ws + (size_t)nblk*PART;
  float* zsp  = zsc + NSNAP*64;
  float* feat = zsp + NSNAP*64;

  hipLaunchKernelGGL(kZ, dim3(1), dim3(64), 0, stream, cw, cb, pa, zsc, zsp);

  if (nblk == 512) {
    (void)hipFuncSetAttribute((const void*)&kA<128>,
        hipFuncAttributeMaxDynamicSharedMemorySize, 128*472);
    hipLaunchKernelGGL(kA<128>, dim3(512), dim3(256), 128*472, stream,
                       x, w0, cw, cb, pa, partial);
  } else {
    (void)hipFuncSetAttribute((const void*)&kA<256>,
        hipFuncAttributeMaxDynamicSharedMemorySize, 256*472);
    hipLaunchKernelGGL(kA<256>, dim3(256), dim3(256), 256*472, stream,
                       x, w0, cw, cb, pa, partial);
  }

  hipLaunchKernelGGL(kB, dim3(86), dim3(256), 0, stream,
                     partial, nblk, zsc, zsp, pa, feat);
  hipLaunchKernelGGL(kC, dim3(32, 18), dim3(256), 0, stream, feat, fcw, fcb, out);
}

// Round 3
// 387.697 us; speedup vs baseline: 2.2915x; 2.2915x over previous
//
#include <hip/hip_runtime.h>

#define NSET 38
#define NSNAP 9
#define PART (NSNAP*NSET*64)   // 21888 floats of partial per block
#define PPB 128
#define ZSTR 65                // zt row stride (65: conflict-free b32 everywhere)

// LDS: zt[128][65] f32 | addend[128][48] f32 | memb32[128][2] u32 = 58880 B
#define KA_LDS (PPB*ZSTR*4 + PPB*48*4 + PPB*2*4)

typedef unsigned long long ull;

// kA<CHUNKS>: each block processes CHUNKS sequential chunks of 128 points.
// 256 threads: thread t -> point q=t&127, dim-half h=t>>7 (wave-uniform).
template<int CHUNKS>
__global__ __launch_bounds__(256) __attribute__((amdgpu_waves_per_eu(2, 2)))
void kA(const int* __restrict__ x, const float* __restrict__ w0,
        const float* __restrict__ cw, const float* __restrict__ cb,
        const float* __restrict__ pa, float* __restrict__ partial)
{
  extern __shared__ __align__(16) char smem[];
  float* zt = (float*)smem;                        // [128][65]
  float* addend = zt + PPB*ZSTR;                   // [128][48]
  unsigned* memb32 = (unsigned*)(addend + PPB*48); // [128][2]

  const int tid = threadIdx.x;
  const int q  = tid & 127;
  const int hd = tid >> 7;                                    // divergent form
  const int h  = __builtin_amdgcn_readfirstlane(tid >> 7);    // wave-uniform!
  const int d0 = tid & 63;
  const int g  = tid >> 6;

  #pragma unroll 1
  for (int c = 0; c < CHUNKS; ++c) {
    const int p = (blockIdx.x*CHUNKS + c)*PPB + q;

    // membership: 19 sets per (q,h); coalesced loads
    unsigned m = 0;
    #pragma unroll
    for (int j = 0; j < 19; ++j)
      m |= (unsigned)(x[(hd*19 + j)*65536 + p] == 1) << j;
    if (c) __syncthreads();           // prior chunk's LDS reads done
    memb32[q*2 + hd] = m;
    __syncthreads();

    // addend[q][set] = member ? 0 : -1e38 ; consecutive-i writes (no conflicts)
    #pragma unroll 1
    for (int i = tid; i < PPB*48; i += 256) {
      int qq = i / 48, j = i - qq*48;
      unsigned mm = (j < 19) ? memb32[qq*2] : memb32[qq*2 + 1];
      int jj = (j < 19) ? j : j - 19;
      addend[i] = (j < NSET && ((mm >> jj) & 1u)) ? 0.f : -1e38f;
    }

    // conv0: pre-act for dims [32h, 32h+32) of point q (weights via s_load)
    float acc[32];
    {
      float px = -1.f + (2.f/255.f)*(float)(p & 255);
      float py = -1.f + (2.f/255.f)*(float)(p >> 8);
      #pragma unroll
      for (int d = 0; d < 32; ++d) {
        int dd = (h << 5) + d;
        acc[d] = fmaf(px, w0[2*dd], fmaf(py, w0[2*dd+1], cb[dd]));
      }
    }

    #pragma unroll 1
    for (int s = 0; s < NSNAP; ++s) {
      // prelu -> zt  (pool in PReLU domain; conv-domain recovered in kB)
      __syncthreads();                 // prev snap's zt reads (pool+mlp) done
      #pragma unroll
      for (int d = 0; d < 32; ++d) {
        float zv = acc[d];
        float a = pa[(s << 6) + (h << 5) + d];   // uniform -> s_load
        zt[q*ZSTR + (h << 5) + d] = zv > 0.f ? zv : a*zv;
      }
      __syncthreads();                 // zt ready (and addend, for s==0)

      // pool: thread (d0,g) pools 12 sets over 128 points
      float run[12];
      #pragma unroll
      for (int j = 0; j < 12; ++j) run[j] = -3e38f;
      #pragma unroll 1
      for (int pp = 0; pp < PPB; pp += 2) {
        float v0 = zt[pp*ZSTR + d0];
        float v1 = zt[(pp + 1)*ZSTR + d0];
        const float4* a0 = (const float4*)&addend[pp*48 + g*12];       // b128 broadcast
        const float4* a1 = (const float4*)&addend[(pp + 1)*48 + g*12];
        #pragma unroll
        for (int qq = 0; qq < 3; ++qq) {
          float4 x0 = a0[qq], x1 = a1[qq];
          run[4*qq+0] = fmaxf(fmaxf(run[4*qq+0], v0 + x0.x), v1 + x1.x);
          run[4*qq+1] = fmaxf(fmaxf(run[4*qq+1], v0 + x0.y), v1 + x1.y);
          run[4*qq+2] = fmaxf(fmaxf(run[4*qq+2], v0 + x0.z), v1 + x1.z);
          run[4*qq+3] = fmaxf(fmaxf(run[4*qq+3], v0 + x0.w), v1 + x1.w);
        }
      }
      {
        float* pb = partial + (size_t)blockIdx.x*PART + s*(NSET*64) + d0;
        #pragma unroll
        for (int j = 0; j < 12; ++j) {
          int set = g*12 + j;
          if (set < NSET) {
            if (CHUNKS == 1 || c == 0) pb[set*64] = run[j];
            else                       pb[set*64] = fmaxf(pb[set*64], run[j]);
          }
        }
      }

      // next layer: inputs from LDS (zt), weights via scalar loads
      if (s < 8) {
        float rz[64];
        #pragma unroll
        for (int k = 0; k < 64; ++k) rz[k] = zt[q*ZSTR + k];
        const float* W = cw + (s << 12) + (h << 11);   // rows [32h,32h+32)
        #pragma unroll
        for (int d = 0; d < 32; ++d) {
          float a = cb[((s + 1) << 6) + (h << 5) + d];
          #pragma unroll
          for (int k = 0; k < 64; ++k)
            a = fmaf(rz[k], W[(d << 6) + k], a);
          acc[d] = a;
        }
      }
    }
  }
}

// zero-point snapshots: conv-domain and prelu-domain, 9 x 64 each
__global__ void kZ(const float* __restrict__ cw, const float* __restrict__ cb,
                   const float* __restrict__ pa,
                   float* __restrict__ zsc, float* __restrict__ zsp)
{
  __shared__ float zl[64];
  int d = threadIdx.x;  // 64 threads
  float z = cb[d];
  #pragma unroll 1
  for (int s = 0; s < NSNAP; ++s) {
    zsc[(s << 6) + d] = z;
    float a = pa[(s << 6) + d];
    float zp = z > 0.f ? z : a*z;
    zsp[(s << 6) + d] = zp;
    if (s < 8) {
      __syncthreads();
      zl[d] = zp;
      __syncthreads();
      float acc = cb[((s + 1) << 6) + d];
      for (int k = 0; k < 64; ++k)
        acc = fmaf(zl[k], cw[(s << 12) + (d << 6) + k], acc);
      z = acc;
    }
  }
}

// reduce block partials -> pooled -> feat (conv & prelu snapshots)
__global__ void kB(const float* __restrict__ partial, int nblk,
                   const float* __restrict__ zsc, const float* __restrict__ zsp,
                   const float* __restrict__ pa, float* __restrict__ feat)
{
  int idx = blockIdx.x*256 + threadIdx.x;
  if (idx >= NSNAP*NSET*64) return;
  int s = idx / (NSET*64);
  int r = idx - s*(NSET*64);
  int set = r >> 6;
  int d = r & 63;
  float mx = -3e38f;
  const float* p0 = partial + idx;   // layout [blk][s][set][d] matches idx
  #pragma unroll 4
  for (int blk = 0; blk < nblk; ++blk)
    mx = fmaxf(mx, p0[(size_t)blk*PART]);
  int b = set / 19, cc = set - b*19;
  float even_v, odd_v;
  if (mx < -5e37f) {                 // empty set -> zero-point snapshot
    even_v = zsc[(s << 6) + d];
    odd_v  = zsp[(s << 6) + d];
  } else {
    odd_v = mx;                      // prelu-domain max
    float a = pa[(s << 6) + d];
    even_v = mx > 0.f ? mx : mx / a; // inverse prelu
  }
  size_t fb = ((size_t)b*18 + 2*s)*1216 + cc*64 + d;
  feat[fb] = even_v;
  feat[fb + 1216] = odd_v;
}

// out[b][17-lr][srow] = scale*<feat[b][lr], fcw[lr][srow]> + fcb[lr][srow]
__global__ __launch_bounds__(256) void kC(const float* __restrict__ feat,
    const float* __restrict__ fcw, const float* __restrict__ fcb,
    float* __restrict__ out)
{
  __shared__ float f0[1216], f1[1216];
  int lr = blockIdx.y;
  int chunk = blockIdx.x;       // 0..31, 16 rows each
  int tid = threadIdx.x;
  for (int i = tid; i < 1216; i += 256) {
    f0[i] = feat[(size_t)(0*18 + lr)*1216 + i];
    f1[i] = feat[(size_t)(1*18 + lr)*1216 + i];
  }
  __syncthreads();
  int wv = tid >> 6, lane = tid & 63;
  float scale = 1.f / sqrtf(1216.f);
  int l = 17 - lr;
  #pragma unroll 1
  for (int rr = 0; rr < 4; ++rr) {
    int srow = (chunk << 4) + (wv << 2) + rr;
    const float* wrow = fcw + ((size_t)lr*512 + srow)*1216;
    float pp0 = 0.f, pp1 = 0.f;
    #pragma unroll
    for (int k = 0; k < 19; ++k) {
      float w = wrow[(k << 6) + lane];
      pp0 = fmaf(w, f0[(k << 6) + lane], pp0);
      pp1 = fmaf(w, f1[(k << 6) + lane], pp1);
    }
    #pragma unroll
    for (int off = 32; off; off >>= 1) {
      pp0 += __shfl_xor(pp0, off, 64);
      pp1 += __shfl_xor(pp1, off, 64);
    }
    if (lane == 0) {
      float b = fcb[lr*512 + srow];
      out[((size_t)0*18 + l)*512 + srow] = fmaf(scale, pp0, b);
      out[((size_t)1*18 + l)*512 + srow] = fmaf(scale, pp1, b);
    }
  }
}

extern "C" void kernel_launch(void* const* d_in, const int* in_sizes, int n_in,
                              void* d_out, int out_size, void* d_ws, size_t ws_size,
                              hipStream_t stream) {
  const int*   x   = (const int*)d_in[0];
  const float* w0  = (const float*)d_in[1];
  const float* cw  = (const float*)d_in[2];
  const float* cb  = (const float*)d_in[3];
  const float* pa  = (const float*)d_in[4];
  const float* fcw = (const float*)d_in[5];
  const float* fcb = (const float*)d_in[6];
  float* ws = (float*)d_ws;
  float* out = (float*)d_out;

  const size_t tail = (size_t)NSNAP*64*2 + (size_t)2*18*1216;  // zsc+zsp+feat
  const size_t need512 = ((size_t)512*PART + tail)*4;

  const int nblk = (ws_size >= need512) ? 512 : 256;

  float* partial = ws;
  float* zsc  = ws + (size_t)nblk*PART;
  float* zsp  = zsc + NSNAP*64;
  float* feat = zsp + NSNAP*64;

  hipLaunchKernelGGL(kZ, dim3(1), dim3(64), 0, stream, cw, cb, pa, zsc, zsp);

  if (nblk == 512) {
    hipLaunchKernelGGL(kA<1>, dim3(512), dim3(256), KA_LDS, stream,
                       x, w0, cw, cb, pa, partial);
  } else {
    hipLaunchKernelGGL(kA<2>, dim3(256), dim3(256), KA_LDS, stream,
                       x, w0, cw, cb, pa, partial);
  }

  hipLaunchKernelGGL(kB, dim3(86), dim3(256), 0, stream,
                     partial, nblk, zsc, zsp, pa, feat);
  hipLaunchKernelGGL(kC, dim3(32, 18), dim3(256), 0, stream, feat, fcw, fcb, out);
}